// Round 1
// baseline (776.853 us; speedup 1.0000x reference)
//
#include <hip/hip_runtime.h>
#include <hip/hip_bf16.h>
#include <stdint.h>

#define B_   8
#define C_   512
#define NPIX 4096

typedef __attribute__((ext_vector_type(8))) short bf16x8;
typedef __attribute__((ext_vector_type(4))) float f32x4;

__device__ __forceinline__ uint16_t f2bf(float f) {
    union { float f; uint32_t u; } v; v.f = f;
    uint32_t u = v.u;
    return (uint16_t)((u + 0x7FFFu + ((u >> 16) & 1u)) >> 16);
}

// ---------------- projection: out = W(OxC) * X(CxN) + bias, bf16 output ----
// TRANS=true : out[b][n][o]   (for q_t, k_t; O==64)
// TRANS=false: out[b][o][n]   (for v)
template<bool TRANS>
__global__ __launch_bounds__(256, 2) void proj_kernel(
    const float* __restrict__ X, const float* __restrict__ W,
    const float* __restrict__ bias, uint16_t* __restrict__ out,
    int O, float scale)
{
    __shared__ char xt[64 * 128];   // [n][c] bf16, byte = n*128 + 2c ^ ((n&7)<<4)
    const int b  = blockIdx.z;
    const int o0 = blockIdx.y * 64;
    const int n0 = blockIdx.x * 64;
    const int t = threadIdx.x, w = t >> 6, l = t & 63;
    const int l15 = l & 15, lg = l >> 4;
    const float* Xb = X + (size_t)b * C_ * NPIX + n0;

    f32x4 acc[4] = {};

    for (int cc = 0; cc < C_; cc += 64) {
        __syncthreads();
        // stage chunk: global x[c][n] (n coalesced across lanes) -> lds[n][c] bf16
        #pragma unroll
        for (int i = 0; i < 16; i += 2) {
            int c = w * 16 + i;
            float f0 = Xb[(size_t)(cc + c) * NPIX + l];
            float f1 = Xb[(size_t)(cc + c + 1) * NPIX + l];
            uint32_t pair = (uint32_t)f2bf(f0) | ((uint32_t)f2bf(f1) << 16);
            int byte = (l * 128 + c * 2) ^ ((l & 7) << 4);
            *(uint32_t*)(xt + byte) = pair;
        }
        __syncthreads();
        #pragma unroll
        for (int kk = 0; kk < 2; kk++) {
            int o  = o0 + w * 16 + l15;
            int cb = cc + kk * 32 + lg * 8;
            float4 wa = *(const float4*)&W[(size_t)o * C_ + cb];
            float4 wb = *(const float4*)&W[(size_t)o * C_ + cb + 4];
            bf16x8 af;
            af[0]=f2bf(wa.x); af[1]=f2bf(wa.y); af[2]=f2bf(wa.z); af[3]=f2bf(wa.w);
            af[4]=f2bf(wb.x); af[5]=f2bf(wb.y); af[6]=f2bf(wb.z); af[7]=f2bf(wb.w);
            #pragma unroll
            for (int jt = 0; jt < 4; jt++) {
                int n = jt * 16 + l15;
                int byte = (n * 128 + (kk * 32 + lg * 8) * 2) ^ ((n & 7) << 4);
                bf16x8 bfr = *(bf16x8*)(xt + byte);
                acc[jt] = __builtin_amdgcn_mfma_f32_16x16x32_bf16(af, bfr, acc[jt], 0, 0, 0);
            }
        }
    }
    // epilogue: D[o][n], col=n=lane&15, row(o-local)=(lane>>4)*4+r
    int og = o0 + w * 16 + lg * 4;
    #pragma unroll
    for (int jt = 0; jt < 4; jt++) {
        int n = n0 + jt * 16 + l15;
        #pragma unroll
        for (int r = 0; r < 4; r++) {
            float v = (acc[jt][r] + bias[og + r]) * scale;
            if (TRANS) out[((size_t)b * NPIX + n) * 64 + og + r] = f2bf(v);
            else       out[((size_t)b * (size_t)O + og + r) * NPIX + n] = f2bf(v);
        }
    }
}

// ---------------- fused flash attention + residual epilogue ----------------
// grid (cblk=2, qtile=64, b=8), 4 waves; wave owns 64 V-channels, 64 Q rows.
__global__ __launch_bounds__(256, 2) void attn_kernel(
    const uint16_t* __restrict__ qT, const uint16_t* __restrict__ kT,
    const uint16_t* __restrict__ vB, const float* __restrict__ X,
    const float* __restrict__ gamma_p, float* __restrict__ out)
{
    __shared__ char plds_all[4][64 * 128];  // per-wave P tile [i][j] bf16, swizzled
    const int b  = blockIdx.z;
    const int i0 = blockIdx.y * 64;
    const int t = threadIdx.x, w = t >> 6, l = t & 63;
    const int c0 = blockIdx.x * 256 + w * 64;
    const int l15 = l & 15, lg = l >> 4;
    char* P = plds_all[w];

    // Q fragments (B-operand of swapped QK): q_t[i][d], i=lane&15 per tile
    bf16x8 q8[4][2];
    #pragma unroll
    for (int it = 0; it < 4; it++)
        #pragma unroll
        for (int kk = 0; kk < 2; kk++)
            q8[it][kk] = *(const bf16x8*)&qT[((size_t)b * NPIX + i0 + it*16 + l15) * 64 + kk*32 + lg*8];

    f32x4 oacc[4][4] = {};    // [ct][it] : O^T[c][i]
    float m_i[4], l_i[4];
    #pragma unroll
    for (int it = 0; it < 4; it++) { m_i[it] = -3.0e38f; l_i[it] = 0.0f; }

    const uint16_t* kTb = kT + (size_t)b * NPIX * 64;
    const uint16_t* vBb = vB + ((size_t)b * C_ + c0) * NPIX;

    // preload first K tile (A-operand: k_t[j][d], j=lane&15 per tile)
    bf16x8 k8[4][2];
    #pragma unroll
    for (int jt = 0; jt < 4; jt++)
        #pragma unroll
        for (int kk = 0; kk < 2; kk++)
            k8[jt][kk] = *(const bf16x8*)&kTb[(size_t)(jt*16 + l15) * 64 + kk*32 + lg*8];

    #pragma unroll 1
    for (int j0 = 0; j0 < NPIX; j0 += 64) {
        // S^T[j][i] = sum_d K[j][d] Q[i][d]  (q pre-scaled by log2e)
        f32x4 s[4][4] = {};   // [jt][it]; row(j-local)=lg*4+r, col(i-local)=l15
        #pragma unroll
        for (int kk = 0; kk < 2; kk++)
            #pragma unroll
            for (int jt = 0; jt < 4; jt++)
                #pragma unroll
                for (int it = 0; it < 4; it++)
                    s[jt][it] = __builtin_amdgcn_mfma_f32_16x16x32_bf16(k8[jt][kk], q8[it][kk], s[jt][it], 0, 0, 0);

        // prefetch next K tile (hides under softmax VALU)
        if (j0 + 64 < NPIX) {
            #pragma unroll
            for (int jt = 0; jt < 4; jt++)
                #pragma unroll
                for (int kk = 0; kk < 2; kk++)
                    k8[jt][kk] = *(const bf16x8*)&kTb[(size_t)(j0 + 64 + jt*16 + l15) * 64 + kk*32 + lg*8];
        }

        // online softmax; per-lane i = it*16 + (l&15)
        float fvec[4];
        #pragma unroll
        for (int it = 0; it < 4; it++) {
            float pm = -3.0e38f;
            #pragma unroll
            for (int jt = 0; jt < 4; jt++)
                #pragma unroll
                for (int r = 0; r < 4; r++) pm = fmaxf(pm, s[jt][it][r]);
            pm = fmaxf(pm, __shfl_xor(pm, 16));
            pm = fmaxf(pm, __shfl_xor(pm, 32));
            float mnew = fmaxf(m_i[it], pm);
            float f = exp2f(m_i[it] - mnew);
            m_i[it] = mnew;
            fvec[it] = f;
            float sum = 0.f;
            #pragma unroll
            for (int jt = 0; jt < 4; jt++)
                #pragma unroll
                for (int r = 0; r < 4; r++) {
                    float p = exp2f(s[jt][it][r] - mnew);
                    s[jt][it][r] = p;
                    sum += p;
                }
            sum += __shfl_xor(sum, 16);
            sum += __shfl_xor(sum, 32);
            l_i[it] = l_i[it] * f + sum;
        }
        // rescale O
        #pragma unroll
        for (int ct = 0; ct < 4; ct++)
            #pragma unroll
            for (int it = 0; it < 4; it++)
                #pragma unroll
                for (int r = 0; r < 4; r++)
                    oacc[ct][it][r] *= fvec[it];

        // P -> LDS as [i][j] bf16 (r=0..3 are contiguous j => b64 packed write)
        #pragma unroll
        for (int it = 0; it < 4; it++) {
            int i = it * 16 + l15;
            int rowb = i * 128, swz = (i & 7) << 4;
            #pragma unroll
            for (int jt = 0; jt < 4; jt++) {
                int byte = (rowb + jt * 32 + lg * 8) ^ swz;
                ushort4 pk;
                pk.x = f2bf(s[jt][it][0]); pk.y = f2bf(s[jt][it][1]);
                pk.z = f2bf(s[jt][it][2]); pk.w = f2bf(s[jt][it][3]);
                *(ushort4*)(P + byte) = pk;
            }
        }

        // PV: O^T[c][i] += V[c][j] * P[i][j]
        #pragma unroll
        for (int kk = 0; kk < 2; kk++) {
            bf16x8 pb[4];
            #pragma unroll
            for (int it = 0; it < 4; it++) {
                int i = it * 16 + l15;
                int byte = (i * 128 + kk * 64 + lg * 16) ^ ((i & 7) << 4);
                pb[it] = *(bf16x8*)(P + byte);
            }
            #pragma unroll
            for (int ct = 0; ct < 4; ct++) {
                bf16x8 v8 = *(const bf16x8*)&vBb[(size_t)(ct*16 + l15) * NPIX + j0 + kk*32 + lg*8];
                #pragma unroll
                for (int it = 0; it < 4; it++)
                    oacc[ct][it] = __builtin_amdgcn_mfma_f32_16x16x32_bf16(v8, pb[it], oacc[ct][it], 0, 0, 0);
            }
        }
    }

    // epilogue: out = gamma * (O/l) + x ; coalesced along i (=n)
    float g = gamma_p[0];
    float rl[4];
    #pragma unroll
    for (int it = 0; it < 4; it++) rl[it] = 1.0f / l_i[it];
    #pragma unroll
    for (int ct = 0; ct < 4; ct++)
        #pragma unroll
        for (int r = 0; r < 4; r++) {
            int c = c0 + ct * 16 + lg * 4 + r;
            #pragma unroll
            for (int it = 0; it < 4; it++) {
                int n = i0 + it * 16 + l15;
                size_t idx = ((size_t)b * C_ + c) * NPIX + n;
                out[idx] = g * (oacc[ct][it][r] * rl[it]) + X[idx];
            }
        }
}

extern "C" void kernel_launch(void* const* d_in, const int* in_sizes, int n_in,
                              void* d_out, int out_size, void* d_ws, size_t ws_size,
                              hipStream_t stream) {
    const float* x     = (const float*)d_in[0];
    const float* y     = (const float*)d_in[1];
    const float* z     = (const float*)d_in[2];
    const float* Wq    = (const float*)d_in[3];
    const float* bq    = (const float*)d_in[4];
    const float* Wk    = (const float*)d_in[5];
    const float* bk    = (const float*)d_in[6];
    const float* Wv    = (const float*)d_in[7];
    const float* bv    = (const float*)d_in[8];
    const float* gamma = (const float*)d_in[9];
    float* out = (float*)d_out;

    uint16_t* qT = (uint16_t*)d_ws;                       // [8][4096][64] bf16
    uint16_t* kT = qT + (size_t)B_ * NPIX * 64;           // [8][4096][64] bf16
    uint16_t* vB = kT + (size_t)B_ * NPIX * 64;           // [8][512][4096] bf16

    dim3 blk(256);
    // q pre-scaled by log2(e) so softmax uses exp2 directly
    proj_kernel<true ><<<dim3(64, 1, 8), blk, 0, stream>>>(x, Wq, bq, qT, 64, 1.4426950408889634f);
    proj_kernel<true ><<<dim3(64, 1, 8), blk, 0, stream>>>(y, Wk, bk, kT, 64, 1.0f);
    proj_kernel<false><<<dim3(64, 8, 8), blk, 0, stream>>>(z, Wv, bv, vB, 512, 1.0f);
    attn_kernel<<<dim3(2, 64, 8), blk, 0, stream>>>(qT, kT, vB, x, gamma, out);
}

// Round 2
// 738.012 us; speedup vs baseline: 1.0526x; 1.0526x over previous
//
#include <hip/hip_runtime.h>
#include <hip/hip_bf16.h>
#include <stdint.h>

#define B_   8
#define C_   512
#define NPIX 4096

typedef __attribute__((ext_vector_type(8))) short bf16x8;
typedef __attribute__((ext_vector_type(4))) float f32x4;

__device__ __forceinline__ uint16_t f2bf(float f) {
    union { float f; uint32_t u; } v; v.f = f;
    uint32_t u = v.u;
    return (uint16_t)((u + 0x7FFFu + ((u >> 16) & 1u)) >> 16);
}

// pack 2 floats -> 2 bf16 in a u32 (compiler emits v_cvt_pk_bf16_f32)
__device__ __forceinline__ uint32_t pk2(float a, float b) {
    union { __hip_bfloat162 h; uint32_t u; } c;
    c.h = __float22bfloat162_rn(make_float2(a, b));
    return c.u;
}

// ---------------- projection: out = W(OxC) * X(CxN) + bias, bf16 output ----
// TRANS=true : out[b][n][o]   (for q_t, k_t; O==64)
// TRANS=false: out[b][o][n]   (for v)
template<bool TRANS>
__global__ __launch_bounds__(256, 2) void proj_kernel(
    const float* __restrict__ X, const float* __restrict__ W,
    const float* __restrict__ bias, uint16_t* __restrict__ out,
    int O, float scale)
{
    __shared__ char xt[64 * 128];   // [n][c] bf16, byte = n*128 + 2c ^ ((n&7)<<4)
    const int b  = blockIdx.z;
    const int o0 = blockIdx.y * 64;
    const int n0 = blockIdx.x * 64;
    const int t = threadIdx.x, w = t >> 6, l = t & 63;
    const int l15 = l & 15, lg = l >> 4;
    const float* Xb = X + (size_t)b * C_ * NPIX + n0;

    f32x4 acc[4] = {};

    for (int cc = 0; cc < C_; cc += 64) {
        __syncthreads();
        #pragma unroll
        for (int i = 0; i < 16; i += 2) {
            int c = w * 16 + i;
            float f0 = Xb[(size_t)(cc + c) * NPIX + l];
            float f1 = Xb[(size_t)(cc + c + 1) * NPIX + l];
            uint32_t pair = (uint32_t)f2bf(f0) | ((uint32_t)f2bf(f1) << 16);
            int byte = (l * 128 + c * 2) ^ ((l & 7) << 4);
            *(uint32_t*)(xt + byte) = pair;
        }
        __syncthreads();
        #pragma unroll
        for (int kk = 0; kk < 2; kk++) {
            int o  = o0 + w * 16 + l15;
            int cb = cc + kk * 32 + lg * 8;
            float4 wa = *(const float4*)&W[(size_t)o * C_ + cb];
            float4 wb = *(const float4*)&W[(size_t)o * C_ + cb + 4];
            bf16x8 af;
            af[0]=f2bf(wa.x); af[1]=f2bf(wa.y); af[2]=f2bf(wa.z); af[3]=f2bf(wa.w);
            af[4]=f2bf(wb.x); af[5]=f2bf(wb.y); af[6]=f2bf(wb.z); af[7]=f2bf(wb.w);
            #pragma unroll
            for (int jt = 0; jt < 4; jt++) {
                int n = jt * 16 + l15;
                int byte = (n * 128 + (kk * 32 + lg * 8) * 2) ^ ((n & 7) << 4);
                bf16x8 bfr = *(bf16x8*)(xt + byte);
                acc[jt] = __builtin_amdgcn_mfma_f32_16x16x32_bf16(af, bfr, acc[jt], 0, 0, 0);
            }
        }
    }
    int og = o0 + w * 16 + lg * 4;
    #pragma unroll
    for (int jt = 0; jt < 4; jt++) {
        int n = n0 + jt * 16 + l15;
        #pragma unroll
        for (int r = 0; r < 4; r++) {
            float v = (acc[jt][r] + bias[og + r]) * scale;
            if (TRANS) out[((size_t)b * NPIX + n) * 64 + og + r] = f2bf(v);
            else       out[((size_t)b * (size_t)O + og + r) * NPIX + n] = f2bf(v);
        }
    }
}

// ---------------- fused flash attention, shared softmax across waves -------
// 1D grid of 1024 blocks; block = (qtile 64 rows) x (256 channels).
// 4 waves: wave w computes S for j-slice [w*16, w*16+16) of each 64-j KV step,
// softmax merged via LDS exchange; P shared in LDS; PV per-wave 64-ch slice.
__global__ __launch_bounds__(256, 3) void attn_kernel(
    const uint16_t* __restrict__ qT, const uint16_t* __restrict__ kT,
    const uint16_t* __restrict__ vB, const float* __restrict__ X,
    const float* __restrict__ gamma_p, float* __restrict__ out)
{
    __shared__ char   Pl[64 * 128];   // P[i][j] bf16, byte = i*128+2j ^ ((i&7)<<4)
    __shared__ float2 xch[64][4];     // [i][wave] = (rowmax, sum exp2(s-rowmax))

    // XCD-group swizzle: group g=(b,cb); 64 qtile-blocks of a group land on one XCD
    const int id  = blockIdx.x;
    const int xcd = id & 7, slot = id >> 3;
    const int g   = xcd + 8 * (slot >> 6);     // 16 groups
    const int qt  = slot & 63;
    const int b   = g >> 1, cb = g & 1;
    const int i0  = qt * 64;

    const int t = threadIdx.x, w = t >> 6, l = t & 63;
    const int l15 = l & 15, lg = l >> 4;
    const int c0 = cb * 256 + w * 64;

    // Q fragments (B-operand of swapped QK): col i = l15, k-elems d = lg*8..
    bf16x8 q8[4][2];
    #pragma unroll
    for (int it = 0; it < 4; it++)
        #pragma unroll
        for (int kk = 0; kk < 2; kk++)
            q8[it][kk] = *(const bf16x8*)&qT[((size_t)b * NPIX + i0 + it*16 + l15) * 64 + kk*32 + lg*8];

    f32x4 oacc[4][4] = {};    // [ct][it] : O^T[c][i]
    float m_i[4], l_i[4];
    #pragma unroll
    for (int it = 0; it < 4; it++) { m_i[it] = -3.0e38f; l_i[it] = 0.0f; }

    const uint16_t* kTb = kT + (size_t)b * NPIX * 64;
    const uint16_t* vBb = vB + ((size_t)b * C_ + c0) * NPIX;
    // this wave's K row pointer: A-frag row = l15 within its 16-j slice
    const uint16_t* kROW = kTb + (size_t)(w * 16 + l15) * 64 + lg * 8;

    bf16x8 k8[2];
    k8[0] = *(const bf16x8*)(kROW);
    k8[1] = *(const bf16x8*)(kROW + 32);

    #pragma unroll 1
    for (int j0 = 0; j0 < NPIX; j0 += 64) {
        // S^T slice: rows j = j0 + w*16 + lg*4 + r, cols i = it*16 + l15
        f32x4 s[4] = {};
        #pragma unroll
        for (int kk = 0; kk < 2; kk++)
            #pragma unroll
            for (int it = 0; it < 4; it++)
                s[it] = __builtin_amdgcn_mfma_f32_16x16x32_bf16(k8[kk], q8[it][kk], s[it], 0, 0, 0);

        // prefetch next K slice (register double-buffer not needed: WAR is safe)
        if (j0 + 64 < NPIX) {
            const uint16_t* kn = kROW + (size_t)(j0 + 64) * 64;
            k8[0] = *(const bf16x8*)(kn);
            k8[1] = *(const bf16x8*)(kn + 32);
        }

        // per-wave partials over its 16 j: rowmax + sum of exp2(s - rowmax)
        float pmw[4], sww[4];
        #pragma unroll
        for (int it = 0; it < 4; it++) {
            f32x4 sv = s[it];
            float pm = fmaxf(fmaxf(sv[0], sv[1]), fmaxf(sv[2], sv[3]));
            pm = fmaxf(pm, __shfl_xor(pm, 16));
            pm = fmaxf(pm, __shfl_xor(pm, 32));
            float e0 = exp2f(sv[0] - pm), e1 = exp2f(sv[1] - pm);
            float e2 = exp2f(sv[2] - pm), e3 = exp2f(sv[3] - pm);
            s[it][0] = e0; s[it][1] = e1; s[it][2] = e2; s[it][3] = e3;
            float s4 = (e0 + e1) + (e2 + e3);
            s4 += __shfl_xor(s4, 16);
            s4 += __shfl_xor(s4, 32);
            pmw[it] = pm; sww[it] = s4;
            if (lg == 0) xch[it * 16 + l15][w] = make_float2(pm, s4);
        }
        __syncthreads();

        // merge across the 4 waves; defer-max (THR=8) skips O-rescale
        float scw[4];
        #pragma unroll
        for (int it = 0; it < 4; it++) {
            int i = it * 16 + l15;
            float2 t0 = xch[i][0], t1 = xch[i][1], t2 = xch[i][2], t3 = xch[i][3];
            float pmax = fmaxf(fmaxf(t0.x, t1.x), fmaxf(t2.x, t3.x));
            if (__any(pmax > m_i[it] + 8.0f)) {
                float mnew = fmaxf(m_i[it], pmax);
                float f = exp2f(m_i[it] - mnew);
                m_i[it] = mnew;
                l_i[it] *= f;
                #pragma unroll
                for (int ct = 0; ct < 4; ct++)
                    #pragma unroll
                    for (int r = 0; r < 4; r++) oacc[ct][it][r] *= f;
            }
            float m = m_i[it];
            float a0 = exp2f(t0.x - m), a1 = exp2f(t1.x - m);
            float a2 = exp2f(t2.x - m), a3 = exp2f(t3.x - m);
            l_i[it] += t0.y * a0 + t1.y * a1 + t2.y * a2 + t3.y * a3;
            scw[it] = (w < 2) ? (w == 0 ? a0 : a1) : (w == 2 ? a2 : a3);
        }

        // P write: this wave's 16-j slice for all 64 i
        #pragma unroll
        for (int it = 0; it < 4; it++) {
            int i = it * 16 + l15;
            int byte = (i * 128 + (w * 16 + lg * 4) * 2) ^ ((i & 7) << 4);
            float sc = scw[it];
            uint2 pk;
            pk.x = pk2(s[it][0] * sc, s[it][1] * sc);
            pk.y = pk2(s[it][2] * sc, s[it][3] * sc);
            *(uint2*)(Pl + byte) = pk;
        }
        __syncthreads();

        // PV: O^T[c][i] += V[c][j] * P[i][j]  (full 64-j step, shared P)
        #pragma unroll
        for (int kk = 0; kk < 2; kk++) {
            bf16x8 pb[4];
            #pragma unroll
            for (int it = 0; it < 4; it++) {
                int i = it * 16 + l15;
                int byte = (i * 128 + kk * 64 + lg * 16) ^ ((i & 7) << 4);
                pb[it] = *(bf16x8*)(Pl + byte);
            }
            #pragma unroll
            for (int ct = 0; ct < 4; ct++) {
                bf16x8 v8 = *(const bf16x8*)&vBb[(size_t)(ct*16 + l15) * NPIX + j0 + kk*32 + lg*8];
                #pragma unroll
                for (int it = 0; it < 4; it++)
                    oacc[ct][it] = __builtin_amdgcn_mfma_f32_16x16x32_bf16(v8, pb[it], oacc[ct][it], 0, 0, 0);
            }
        }
    }

    // epilogue: out = gamma * (O/l) + x ; coalesced along i (=n)
    float gamma = gamma_p[0];
    float rl[4];
    #pragma unroll
    for (int it = 0; it < 4; it++) rl[it] = 1.0f / l_i[it];
    #pragma unroll
    for (int ct = 0; ct < 4; ct++)
        #pragma unroll
        for (int r = 0; r < 4; r++) {
            int c = c0 + ct * 16 + lg * 4 + r;
            #pragma unroll
            for (int it = 0; it < 4; it++) {
                int n = i0 + it * 16 + l15;
                size_t idx = ((size_t)b * C_ + c) * NPIX + n;
                out[idx] = gamma * (oacc[ct][it][r] * rl[it]) + X[idx];
            }
        }
}

extern "C" void kernel_launch(void* const* d_in, const int* in_sizes, int n_in,
                              void* d_out, int out_size, void* d_ws, size_t ws_size,
                              hipStream_t stream) {
    const float* x     = (const float*)d_in[0];
    const float* y     = (const float*)d_in[1];
    const float* z     = (const float*)d_in[2];
    const float* Wq    = (const float*)d_in[3];
    const float* bq    = (const float*)d_in[4];
    const float* Wk    = (const float*)d_in[5];
    const float* bk    = (const float*)d_in[6];
    const float* Wv    = (const float*)d_in[7];
    const float* bv    = (const float*)d_in[8];
    const float* gamma = (const float*)d_in[9];
    float* out = (float*)d_out;

    uint16_t* qT = (uint16_t*)d_ws;                       // [8][4096][64] bf16
    uint16_t* kT = qT + (size_t)B_ * NPIX * 64;           // [8][4096][64] bf16
    uint16_t* vB = kT + (size_t)B_ * NPIX * 64;           // [8][512][4096] bf16

    dim3 blk(256);
    // q pre-scaled by log2(e) so softmax uses exp2 directly
    proj_kernel<true ><<<dim3(64, 1, 8), blk, 0, stream>>>(x, Wq, bq, qT, 64, 1.4426950408889634f);
    proj_kernel<true ><<<dim3(64, 1, 8), blk, 0, stream>>>(y, Wk, bk, kT, 64, 1.0f);
    proj_kernel<false><<<dim3(64, 8, 8), blk, 0, stream>>>(z, Wv, bv, vB, 512, 1.0f);
    attn_kernel<<<dim3(1024), blk, 0, stream>>>(qT, kT, vB, x, gamma, out);
}

// Round 3
// 494.977 us; speedup vs baseline: 1.5695x; 1.4910x over previous
//
#include <hip/hip_runtime.h>
#include <hip/hip_bf16.h>
#include <stdint.h>

#define B_   8
#define C_   512
#define NPIX 4096

typedef __attribute__((ext_vector_type(8))) short bf16x8;
typedef __attribute__((ext_vector_type(4))) float f32x4;

__device__ __forceinline__ uint16_t f2bf(float f) {
    union { float f; uint32_t u; } v; v.f = f;
    uint32_t u = v.u;
    return (uint16_t)((u + 0x7FFFu + ((u >> 16) & 1u)) >> 16);
}

// pack 2 floats -> 2 bf16 in a u32 (compiler emits v_cvt_pk_bf16_f32)
__device__ __forceinline__ uint32_t pk2(float a, float b) {
    union { __hip_bfloat162 h; uint32_t u; } c;
    c.h = __float22bfloat162_rn(make_float2(a, b));
    return c.u;
}

// ---------------- projection: out = W(OxC) * X(CxN) + bias, bf16 output ----
// TRANS=true : out[b][n][o]   (for q_t, k_t; O==64)
// TRANS=false: out[b][o][n]   (for v)
template<bool TRANS>
__global__ __launch_bounds__(256, 2) void proj_kernel(
    const float* __restrict__ X, const float* __restrict__ W,
    const float* __restrict__ bias, uint16_t* __restrict__ out,
    int O, float scale)
{
    __shared__ char xt[64 * 128];   // [n][c] bf16, byte = n*128 + 2c ^ ((n&7)<<4)
    const int b  = blockIdx.z;
    const int o0 = blockIdx.y * 64;
    const int n0 = blockIdx.x * 64;
    const int t = threadIdx.x, w = t >> 6, l = t & 63;
    const int l15 = l & 15, lg = l >> 4;
    const float* Xb = X + (size_t)b * C_ * NPIX + n0;

    f32x4 acc[4] = {};

    for (int cc = 0; cc < C_; cc += 64) {
        __syncthreads();
        #pragma unroll
        for (int i = 0; i < 16; i += 2) {
            int c = w * 16 + i;
            float f0 = Xb[(size_t)(cc + c) * NPIX + l];
            float f1 = Xb[(size_t)(cc + c + 1) * NPIX + l];
            uint32_t pair = pk2(f0, f1);
            int byte = (l * 128 + c * 2) ^ ((l & 7) << 4);
            *(uint32_t*)(xt + byte) = pair;
        }
        __syncthreads();
        #pragma unroll
        for (int kk = 0; kk < 2; kk++) {
            int o  = o0 + w * 16 + l15;
            int cb = cc + kk * 32 + lg * 8;
            float4 wa = *(const float4*)&W[(size_t)o * C_ + cb];
            float4 wb = *(const float4*)&W[(size_t)o * C_ + cb + 4];
            union { bf16x8 v; uint32_t u[4]; } afu;
            afu.u[0] = pk2(wa.x, wa.y); afu.u[1] = pk2(wa.z, wa.w);
            afu.u[2] = pk2(wb.x, wb.y); afu.u[3] = pk2(wb.z, wb.w);
            #pragma unroll
            for (int jt = 0; jt < 4; jt++) {
                int n = jt * 16 + l15;
                int byte = (n * 128 + (kk * 32 + lg * 8) * 2) ^ ((n & 7) << 4);
                bf16x8 bfr = *(bf16x8*)(xt + byte);
                acc[jt] = __builtin_amdgcn_mfma_f32_16x16x32_bf16(afu.v, bfr, acc[jt], 0, 0, 0);
            }
        }
    }
    int og = o0 + w * 16 + lg * 4;
    #pragma unroll
    for (int jt = 0; jt < 4; jt++) {
        int n = n0 + jt * 16 + l15;
        #pragma unroll
        for (int r = 0; r < 4; r++) {
            float v = (acc[jt][r] + bias[og + r]) * scale;
            if (TRANS) out[((size_t)b * NPIX + n) * 64 + og + r] = f2bf(v);
            else       out[((size_t)b * (size_t)O + og + r) * NPIX + n] = f2bf(v);
        }
    }
}

// ---------------- fused flash attention, software-pipelined ----------------
// 1024 blocks; block = (qtile 64 rows) x (256 channels); 4 waves share softmax.
// Single barrier per 64-j step: double-buffered P + xch; V reg-prefetch.
__global__ __launch_bounds__(256, 2) void attn_kernel(
    const uint16_t* __restrict__ qT, const uint16_t* __restrict__ kT,
    const uint16_t* __restrict__ vB, const float* __restrict__ X,
    const float* __restrict__ gamma_p, float* __restrict__ out)
{
    __shared__ char   Pl[2][64 * 128];   // P[i][j] bf16, byte=i*128+2j ^ ((i&7)<<4)
    __shared__ float2 xch[2][64][5];     // [buf][i][wave], padded stride 5

    const int id  = blockIdx.x;
    const int xcd = id & 7, slot = id >> 3;
    const int g   = xcd + 8 * (slot >> 6);     // 16 groups of 64 blocks per XCD
    const int qt  = slot & 63;
    const int b   = g >> 1, cb = g & 1;
    const int i0  = qt * 64;

    const int t = threadIdx.x, w = t >> 6, l = t & 63;
    const int l15 = l & 15, lg = l >> 4;
    const int c0 = cb * 256 + w * 64;

    // Q fragments (B-operand of swapped QK): col i = l15, k-elems d = lg*8..
    bf16x8 q8[4][2];
    #pragma unroll
    for (int it = 0; it < 4; it++)
        #pragma unroll
        for (int kk = 0; kk < 2; kk++)
            q8[it][kk] = *(const bf16x8*)&qT[((size_t)b * NPIX + i0 + it*16 + l15) * 64 + kk*32 + lg*8];

    f32x4 oacc[4][4] = {};    // [ct][it] : O^T[c][i]
    float m_i[4], l_i[4];
    #pragma unroll
    for (int it = 0; it < 4; it++) { m_i[it] = -3.0e38f; l_i[it] = 0.0f; }

    const uint16_t* kTb = kT + (size_t)b * NPIX * 64;
    const uint16_t* vBb = vB + ((size_t)b * C_ + c0) * NPIX;
    const uint16_t* kROW = kTb + (size_t)(w * 16 + l15) * 64 + lg * 8;

    bf16x8 k8[2], vreg[8];
    f32x4 s[4];
    float scw[4];

    auto loadK = [&](int step) {
        const uint16_t* p = kROW + (size_t)step * (64 * 64);
        k8[0] = *(const bf16x8*)p;
        k8[1] = *(const bf16x8*)(p + 32);
    };
    auto loadV = [&](int step) {
        const uint16_t* p = vBb + step * 64 + lg * 8;
        #pragma unroll
        for (int kk = 0; kk < 2; kk++)
            #pragma unroll
            for (int ct = 0; ct < 4; ct++)
                vreg[kk*4+ct] = *(const bf16x8*)(p + (size_t)(ct*16 + l15) * NPIX + kk*32);
    };
    auto QK = [&]() {
        #pragma unroll
        for (int it = 0; it < 4; it++) s[it] = f32x4{0.f, 0.f, 0.f, 0.f};
        #pragma unroll
        for (int kk = 0; kk < 2; kk++)
            #pragma unroll
            for (int it = 0; it < 4; it++)
                s[it] = __builtin_amdgcn_mfma_f32_16x16x32_bf16(k8[kk], q8[it][kk], s[it], 0, 0, 0);
    };
    auto partials = [&](int buf) {
        #pragma unroll
        for (int it = 0; it < 4; it++) {
            f32x4 sv = s[it];
            float pm = fmaxf(fmaxf(sv[0], sv[1]), fmaxf(sv[2], sv[3]));
            pm = fmaxf(pm, __shfl_xor(pm, 16));
            pm = fmaxf(pm, __shfl_xor(pm, 32));
            float e0 = exp2f(sv[0]-pm), e1 = exp2f(sv[1]-pm);
            float e2 = exp2f(sv[2]-pm), e3 = exp2f(sv[3]-pm);
            s[it][0] = e0; s[it][1] = e1; s[it][2] = e2; s[it][3] = e3;
            float s4 = (e0 + e1) + (e2 + e3);
            s4 += __shfl_xor(s4, 16);
            s4 += __shfl_xor(s4, 32);
            if (lg == 0) xch[buf][it*16 + l15][w] = make_float2(pm, s4);
        }
    };
    auto merge = [&](int buf) {
        #pragma unroll
        for (int it = 0; it < 4; it++) {
            int i = it * 16 + l15;
            float2 t0 = xch[buf][i][0], t1 = xch[buf][i][1];
            float2 t2 = xch[buf][i][2], t3 = xch[buf][i][3];
            float pmax = fmaxf(fmaxf(t0.x, t1.x), fmaxf(t2.x, t3.x));
            if (__any(pmax > m_i[it] + 8.0f)) {
                float mnew = fmaxf(m_i[it], pmax);
                float f = exp2f(m_i[it] - mnew);
                m_i[it] = mnew; l_i[it] *= f;
                #pragma unroll
                for (int ct = 0; ct < 4; ct++)
                    #pragma unroll
                    for (int r = 0; r < 4; r++) oacc[ct][it][r] *= f;
            }
            float m = m_i[it];
            float a0 = exp2f(t0.x - m), a1 = exp2f(t1.x - m);
            float a2 = exp2f(t2.x - m), a3 = exp2f(t3.x - m);
            l_i[it] += t0.y*a0 + t1.y*a1 + t2.y*a2 + t3.y*a3;
            scw[it] = (w < 2) ? (w == 0 ? a0 : a1) : (w == 2 ? a2 : a3);
        }
    };
    auto pwrite = [&](char* P) {
        #pragma unroll
        for (int it = 0; it < 4; it++) {
            int i = it * 16 + l15;
            int byte = (i * 128 + (w * 16 + lg * 4) * 2) ^ ((i & 7) << 4);
            float sc = scw[it];
            uint2 pk;
            pk.x = pk2(s[it][0]*sc, s[it][1]*sc);
            pk.y = pk2(s[it][2]*sc, s[it][3]*sc);
            *(uint2*)(P + byte) = pk;
        }
    };
    auto PV = [&](const char* P) {
        __builtin_amdgcn_s_setprio(1);
        #pragma unroll
        for (int kk = 0; kk < 2; kk++) {
            bf16x8 pb[4];
            #pragma unroll
            for (int it = 0; it < 4; it++) {
                int i = it * 16 + l15;
                int byte = (i * 128 + kk * 64 + lg * 16) ^ ((i & 7) << 4);
                pb[it] = *(const bf16x8*)(P + byte);
            }
            #pragma unroll
            for (int ct = 0; ct < 4; ct++) {
                bf16x8 v8 = vreg[kk*4 + ct];
                #pragma unroll
                for (int it = 0; it < 4; it++)
                    oacc[ct][it] = __builtin_amdgcn_mfma_f32_16x16x32_bf16(v8, pb[it], oacc[ct][it], 0, 0, 0);
            }
        }
        __builtin_amdgcn_s_setprio(0);
    };

    // ---- prologue: step 0 QK/partials; prefetch V(0), K(1) ----
    loadK(0);
    QK();
    partials(0);
    loadV(0);
    loadK(1);
    __syncthreads();
    merge(0);
    pwrite(Pl[0]);
    QK();               // step 1 (k8 = K(1))
    loadK(2);
    partials(1);

    // ---- steady state: 1 barrier per step ----
    #pragma unroll 1
    for (int jt_ = 1; jt_ < 64; ++jt_) {
        __syncthreads();
        PV(Pl[(jt_ - 1) & 1]);      // uses vreg = V(jt_-1)
        loadV(jt_);
        merge(jt_ & 1);
        pwrite(Pl[jt_ & 1]);
        if (jt_ < 63) {
            QK();                   // step jt_+1 (k8 = K(jt_+1))
            if (jt_ < 62) loadK(jt_ + 2);
            partials((jt_ + 1) & 1);
        }
    }
    __syncthreads();
    PV(Pl[1]);                      // step 63

    // ---- epilogue: out = gamma * (O/l) + x ; coalesced along i (=n) ----
    float gamma = gamma_p[0];
    float rl[4];
    #pragma unroll
    for (int it = 0; it < 4; it++) rl[it] = 1.0f / l_i[it];
    #pragma unroll
    for (int ct = 0; ct < 4; ct++)
        #pragma unroll
        for (int r = 0; r < 4; r++) {
            int c = c0 + ct * 16 + lg * 4 + r;
            #pragma unroll
            for (int it = 0; it < 4; it++) {
                int n = i0 + it * 16 + l15;
                size_t idx = ((size_t)b * C_ + c) * NPIX + n;
                out[idx] = gamma * (oacc[ct][it][r] * rl[it]) + X[idx];
            }
        }
}

extern "C" void kernel_launch(void* const* d_in, const int* in_sizes, int n_in,
                              void* d_out, int out_size, void* d_ws, size_t ws_size,
                              hipStream_t stream) {
    const float* x     = (const float*)d_in[0];
    const float* y     = (const float*)d_in[1];
    const float* z     = (const float*)d_in[2];
    const float* Wq    = (const float*)d_in[3];
    const float* bq    = (const float*)d_in[4];
    const float* Wk    = (const float*)d_in[5];
    const float* bk    = (const float*)d_in[6];
    const float* Wv    = (const float*)d_in[7];
    const float* bv    = (const float*)d_in[8];
    const float* gamma = (const float*)d_in[9];
    float* out = (float*)d_out;

    uint16_t* qT = (uint16_t*)d_ws;                       // [8][4096][64] bf16
    uint16_t* kT = qT + (size_t)B_ * NPIX * 64;           // [8][4096][64] bf16
    uint16_t* vB = kT + (size_t)B_ * NPIX * 64;           // [8][512][4096] bf16

    dim3 blk(256);
    // q pre-scaled by log2(e) so softmax uses exp2 directly
    proj_kernel<true ><<<dim3(64, 1, 8), blk, 0, stream>>>(x, Wq, bq, qT, 64, 1.4426950408889634f);
    proj_kernel<true ><<<dim3(64, 1, 8), blk, 0, stream>>>(y, Wk, bk, kT, 64, 1.0f);
    proj_kernel<false><<<dim3(64, 8, 8), blk, 0, stream>>>(z, Wv, bv, vB, 512, 1.0f);
    attn_kernel<<<dim3(1024), blk, 0, stream>>>(qT, kT, vB, x, gamma, out);
}